// Round 3
// baseline (300.112 us; speedup 1.0000x reference)
//
#include <hip/hip_runtime.h>
#include <hip/hip_bf16.h>

// LSTM cell fused kernel for MI355X (gfx950).
// B=65536, H=256. Packed GEMM [B,256]x[256,1024] bf16 MFMA + fused gates.
// R3: transposed MFMA (weights as A-operand, j-permuted pack) -> lane owns 8
//     consecutive j for one row -> float4 full-line stores; persistent blocks
//     (grid=256, T=8 tiles) with double-buffered LDS pipeline; bias folded
//     into accumulator init via LDS.

typedef __attribute__((ext_vector_type(8))) short short8;   // 8 bf16
typedef __attribute__((ext_vector_type(4))) float f32x4;

static constexpr int Bsz   = 65536;
static constexpr int Hdim  = 256;
static constexpr int TROWS = 32;                 // rows per tile
static constexpr int TPB   = 8;                  // tiles per block
static constexpr int GRID  = Bsz / (TROWS * TPB); // 256 blocks, 1/CU

// float -> bf16 bits, round-to-nearest-even
__device__ __forceinline__ short f2bf(float f) {
    unsigned u = __float_as_uint(f);
    return (short)((u + 0x7FFFu + ((u >> 16) & 1u)) >> 16);
}
__device__ __forceinline__ float sigm(float x) { return 1.0f / (1.0f + __expf(-x)); }
__device__ __forceinline__ float tanh_fast(float x) {
    return 2.0f / (1.0f + __expf(-2.0f * x)) - 1.0f;
}

// ---------------------------------------------------------------------------
// Pack Wf,Wc,Wi,Wo ([256,256] fp32, W[j][k]) as bf16 MFMA *A*-operand frags.
// Frag (g, ks, jb, p): lane l, elem e holds W_g[j_actual(l&15)][ks*32+(l>>4)*8+e]
// with j_actual(m) = jb*32 + (m>>2)*8 + p*4 + (m&3)   (j-permutation so the
// output lane gets j = jb*32 + lk*8 + p*4 + reg -> 8 consecutive j per lane).
// flat o = ((((g*8+ks)*8+jb)*2+p)*64 + l)*8 + e ; total 512 KB in d_ws.
// ---------------------------------------------------------------------------
__global__ void __launch_bounds__(256)
prep_w_kernel(const float* __restrict__ Wf, const float* __restrict__ Wc,
              const float* __restrict__ Wi, const float* __restrict__ Wo,
              short* __restrict__ Bp)
{
    int o  = blockIdx.x * 256 + threadIdx.x;   // 0 .. 262143
    int e  = o & 7;
    int l  = (o >> 3) & 63;
    int p  = (o >> 9) & 1;
    int jb = (o >> 10) & 7;
    int ks = (o >> 13) & 7;
    int g  = (o >> 16) & 3;
    int m  = l & 15;
    int k  = ks * 32 + (l >> 4) * 8 + e;
    int j  = jb * 32 + (m >> 2) * 8 + p * 4 + (m & 3);
    const float* W = (g == 0) ? Wf : (g == 1) ? Wc : (g == 2) ? Wi : Wo;
    Bp[o] = f2bf(W[j * 256 + k]);
}

// ---------------------------------------------------------------------------
// Persistent fused kernel. 256 blocks x 512 threads; each block: 8 tiles of
// 32 rows, double-buffered LDS staging of combine (bf16, XOR-swizzled).
// Wave 'wave' owns j-block [wave*32, wave*32+32) for all 4 gates.
// mfma(W_frag, combine_frag): D row-dim = j (perm), col-dim = batch row.
// ---------------------------------------------------------------------------
__global__ void __launch_bounds__(512, 3)
lstm_fused(const float* __restrict__ inp, const float* __restrict__ hid,
           const float* __restrict__ cell, const short* __restrict__ Bp,
           const float* __restrict__ bfv, const float* __restrict__ bcv,
           const float* __restrict__ biv, const float* __restrict__ bov,
           float* __restrict__ out)
{
    __shared__ short As[2][TROWS * Hdim];   // 2 x 16 KB combine tiles
    __shared__ float Blds[4 * Hdim];        // 4 KB biases

    const int tid  = threadIdx.x;
    const int lane = tid & 63;
    const int wave = tid >> 6;
    const int lm   = lane & 15;
    const int lk   = lane >> 4;

    // stage biases once (wave-uniform gate select)
    if (tid < 256) {
        int g  = tid >> 6;
        int j4 = (tid & 63) * 4;
        const float* bp = (g == 0) ? bfv : (g == 1) ? bcv : (g == 2) ? biv : bov;
        *reinterpret_cast<float4*>(&Blds[g * Hdim + j4]) =
            *reinterpret_cast<const float4*>(bp + j4);
    }

    const int rowblk = blockIdx.x * (TROWS * TPB);
    const int r0 = tid >> 5;          // staging row 0..15 (chunk q adds q*16)
    const int k0 = (tid & 31) * 8;    // staging k base 0..248

    float4 L[2][4];                   // pending loads: [chunk][i0,i1,h0,h1]

    auto issue = [&](int t) {
#pragma unroll
        for (int q = 0; q < 2; ++q) {
            const float* ip = inp + (size_t)(rowblk + t * TROWS + r0 + q * 16) * Hdim + k0;
            const float* hp = hid + (size_t)(rowblk + t * TROWS + r0 + q * 16) * Hdim + k0;
            L[q][0] = *reinterpret_cast<const float4*>(ip);
            L[q][1] = *reinterpret_cast<const float4*>(ip + 4);
            L[q][2] = *reinterpret_cast<const float4*>(hp);
            L[q][3] = *reinterpret_cast<const float4*>(hp + 4);
        }
    };
    auto write_lds = [&](int buf) {
#pragma unroll
        for (int q = 0; q < 2; ++q) {
            int row = r0 + q * 16;
            short8 v;
            v[0] = f2bf(L[q][0].x + L[q][2].x);
            v[1] = f2bf(L[q][0].y + L[q][2].y);
            v[2] = f2bf(L[q][0].z + L[q][2].z);
            v[3] = f2bf(L[q][0].w + L[q][2].w);
            v[4] = f2bf(L[q][1].x + L[q][3].x);
            v[5] = f2bf(L[q][1].y + L[q][3].y);
            v[6] = f2bf(L[q][1].z + L[q][3].z);
            v[7] = f2bf(L[q][1].w + L[q][3].w);
            int byte = row * 512 + k0 * 2;
            byte ^= (row & 7) << 4;              // bank-conflict swizzle
            *reinterpret_cast<short8*>(reinterpret_cast<char*>(As[buf]) + byte) = v;
        }
    };

    issue(0);
    write_lds(0);    // compiler inserts vmcnt wait

    float* out0 = out;                               // out gate
    float* out1 = out + (size_t)Bsz * Hdim;          // hidden_state
    float* out2 = out + (size_t)2 * Bsz * Hdim;      // cell_state

#pragma unroll 1
    for (int t = 0; t < TPB; ++t) {
        const int cur = t & 1;
        if (t + 1 < TPB) issue(t + 1);               // prefetch next tile (regs)
        __syncthreads();                             // As[cur] + Blds visible

        // acc init = bias (MFMA accumulates on top)
        f32x4 acc[4][2][2];                          // [gate][nf(rows)][p(j half)]
#pragma unroll
        for (int g = 0; g < 4; ++g)
#pragma unroll
            for (int p = 0; p < 2; ++p) {
                f32x4 b = *reinterpret_cast<const f32x4*>(
                              &Blds[g * Hdim + wave * 32 + lk * 8 + p * 4]);
                acc[g][0][p] = b;
                acc[g][1][p] = b;
            }

        // GEMM: K=256 in 8 steps
#pragma unroll
        for (int ks = 0; ks < 8; ++ks) {
            short8 cf[2];
#pragma unroll
            for (int nf = 0; nf < 2; ++nf) {
                int row  = nf * 16 + lm;
                int byte = row * 512 + (ks * 32 + lk * 8) * 2;
                byte ^= (row & 7) << 4;
                cf[nf] = *reinterpret_cast<const short8*>(
                             reinterpret_cast<const char*>(As[cur]) + byte);
            }
#pragma unroll
            for (int g = 0; g < 4; ++g)
#pragma unroll
                for (int p = 0; p < 2; ++p) {
                    const short8 w = *reinterpret_cast<const short8*>(
                        Bp + (size_t)((((g * 8 + ks) * 8 + wave) * 2 + p) * 64 + lane) * 8);
                    acc[g][0][p] = __builtin_amdgcn_mfma_f32_16x16x32_bf16(w, cf[0], acc[g][0][p], 0, 0, 0);
                    acc[g][1][p] = __builtin_amdgcn_mfma_f32_16x16x32_bf16(w, cf[1], acc[g][1][p], 0, 0, 0);
                }
        }

        // write next tile's combine into the other buffer (loads landed under GEMM)
        if (t + 1 < TPB) write_lds(cur ^ 1);

        // epilogue: lane owns batch row (nf*16+lm) x 8 consecutive j (jq+p*4+r)
        const int jq = wave * 32 + lk * 8;
#pragma unroll
        for (int nf = 0; nf < 2; ++nf) {
            size_t off = (size_t)(rowblk + t * TROWS + nf * 16 + lm) * Hdim + jq;
            f32x4 cv0 = *reinterpret_cast<const f32x4*>(cell + off);
            f32x4 cv1 = *reinterpret_cast<const f32x4*>(cell + off + 4);
            f32x4 o4[2], h4[2], c4[2];
#pragma unroll
            for (int p = 0; p < 2; ++p) {
                const f32x4 cv = p ? cv1 : cv0;
#pragma unroll
                for (int r = 0; r < 4; ++r) {
                    float F = sigm(acc[0][nf][p][r]);
                    float C = tanh_fast(acc[1][nf][p][r]);
                    float I = sigm(sigm(acc[2][nf][p][r]));   // double sigmoid, per ref
                    float O = sigm(acc[3][nf][p][r]);
                    float cs = cv[r] * F + C * I;
                    o4[p][r] = O;
                    h4[p][r] = O * tanh_fast(cs);
                    c4[p][r] = cs;
                }
            }
            // full 128B line per (row, wave) per array: p=0,p=1 back-to-back
            __builtin_nontemporal_store(o4[0], reinterpret_cast<f32x4*>(out0 + off));
            __builtin_nontemporal_store(o4[1], reinterpret_cast<f32x4*>(out0 + off + 4));
            __builtin_nontemporal_store(h4[0], reinterpret_cast<f32x4*>(out1 + off));
            __builtin_nontemporal_store(h4[1], reinterpret_cast<f32x4*>(out1 + off + 4));
            __builtin_nontemporal_store(c4[0], reinterpret_cast<f32x4*>(out2 + off));
            __builtin_nontemporal_store(c4[1], reinterpret_cast<f32x4*>(out2 + off + 4));
        }
    }
}

extern "C" void kernel_launch(void* const* d_in, const int* in_sizes, int n_in,
                              void* d_out, int out_size, void* d_ws, size_t ws_size,
                              hipStream_t stream)
{
    const float* inp  = (const float*)d_in[0];
    const float* hid  = (const float*)d_in[1];
    const float* cell = (const float*)d_in[2];
    const float* Wf   = (const float*)d_in[3];
    const float* bf_  = (const float*)d_in[4];
    const float* Wc   = (const float*)d_in[5];
    const float* bc_  = (const float*)d_in[6];
    const float* Wi   = (const float*)d_in[7];
    const float* bi_  = (const float*)d_in[8];
    const float* Wo   = (const float*)d_in[9];
    const float* bo_  = (const float*)d_in[10];

    short* Bp = (short*)d_ws;    // 512 KB packed bf16 weights

    prep_w_kernel<<<1024, 256, 0, stream>>>(Wf, Wc, Wi, Wo, Bp);
    lstm_fused<<<GRID, 512, 0, stream>>>(inp, hid, cell, Bp,
                                         bf_, bc_, bi_, bo_, (float*)d_out);
}

// Round 4
// 174.901 us; speedup vs baseline: 1.7159x; 1.7159x over previous
//
#include <hip/hip_runtime.h>
#include <hip/hip_bf16.h>

// LSTM cell fused kernel for MI355X (gfx950).
// B=65536, H=256. Packed GEMM [B,256]x[256,1024] bf16 MFMA + fused gates.
// R4: R2 base (verified layout) + double-buffered 2-tile pipeline per block,
//     adjacent half-line stores (no nontemporal), bias folded into acc init.

typedef __attribute__((ext_vector_type(8))) short short8;   // 8 bf16
typedef __attribute__((ext_vector_type(4))) float f32x4;

static constexpr int Bsz   = 65536;
static constexpr int Hdim  = 256;
static constexpr int TROWS = 32;                  // rows per tile
static constexpr int TPB   = 2;                   // tiles per block
static constexpr int GRID  = Bsz / (TROWS * TPB); // 1024 blocks -> 4/CU, 2 resident

// float -> bf16 bits, round-to-nearest-even
__device__ __forceinline__ short f2bf(float f) {
    unsigned u = __float_as_uint(f);
    return (short)((u + 0x7FFFu + ((u >> 16) & 1u)) >> 16);
}
__device__ __forceinline__ float sigm(float x) { return 1.0f / (1.0f + __expf(-x)); }
__device__ __forceinline__ float tanh_fast(float x) {
    return 2.0f / (1.0f + __expf(-2.0f * x)) - 1.0f;
}

// ---------------------------------------------------------------------------
// Pack Wf,Wc,Wi,Wo ([256,256] fp32) into bf16 B-fragment-major layout for
// mfma_f32_16x16x32_bf16 (identical to R2, which verified):
//   flat o = (((g*8 + ks)*16 + jf)*64 + lane)*8 + e
//   k = ks*32 + (lane>>4)*8 + e ;  j = jf*16 + (lane&15) ;  B[k][j] = W_g[j][k]
// ---------------------------------------------------------------------------
__global__ void __launch_bounds__(256)
prep_w_kernel(const float* __restrict__ Wf, const float* __restrict__ Wc,
              const float* __restrict__ Wi, const float* __restrict__ Wo,
              short* __restrict__ Bp)
{
    int o    = blockIdx.x * 256 + threadIdx.x;   // 0 .. 262143
    int e    = o & 7;
    int lane = (o >> 3) & 63;
    int jf   = (o >> 9) & 15;
    int ks   = (o >> 13) & 7;
    int g    = (o >> 16) & 3;
    int k = ks * 32 + (lane >> 4) * 8 + e;
    int j = jf * 16 + (lane & 15);
    const float* W = (g == 0) ? Wf : (g == 1) ? Wc : (g == 2) ? Wi : Wo;
    Bp[o] = f2bf(W[j * 256 + k]);
}

// ---------------------------------------------------------------------------
// Main fused kernel. Block = 512 threads, 2 tiles of 32 rows, dbuf LDS.
// Wave w owns gate-cols [w*32, w*32+32) for ALL 4 gates (R2 assignment).
// acc[4][2][2] = 64 regs; prefetch regs only live in epilogue half 1.
// ---------------------------------------------------------------------------
__global__ void __launch_bounds__(512, 4)
lstm_fused(const float* __restrict__ inp, const float* __restrict__ hid,
           const float* __restrict__ cell, const short* __restrict__ Bp,
           const float* __restrict__ bfv, const float* __restrict__ bcv,
           const float* __restrict__ biv, const float* __restrict__ bov,
           float* __restrict__ out)
{
    __shared__ short As[2][TROWS * Hdim];   // 2 x 16 KB combine tiles (swizzled)
    __shared__ float Blds[4 * Hdim];        // 4 KB biases

    const int tid  = threadIdx.x;
    const int lane = tid & 63;
    const int wave = tid >> 6;
    const int lm   = lane & 15;
    const int lk   = lane >> 4;

    // stage biases once
    if (tid < 256) {
        int g  = tid >> 6;
        int j4 = (tid & 63) * 4;
        const float* bp = (g == 0) ? bfv : (g == 1) ? bcv : (g == 2) ? biv : bov;
        *reinterpret_cast<float4*>(&Blds[g * Hdim + j4]) =
            *reinterpret_cast<const float4*>(bp + j4);
    }

    const int rowblk = blockIdx.x * (TROWS * TPB);
    const int r0 = tid >> 5;          // staging row 0..15 (+16 for chunk 1)
    const int k0 = (tid & 31) * 8;    // staging k base 0..248

    float4 L[2][4];                   // in-flight loads: [chunk][i0,i1,h0,h1]

    auto issue = [&](int t) {
#pragma unroll
        for (int q = 0; q < 2; ++q) {
            const float* ip = inp + (size_t)(rowblk + t * TROWS + r0 + q * 16) * Hdim + k0;
            const float* hp = hid + (size_t)(rowblk + t * TROWS + r0 + q * 16) * Hdim + k0;
            L[q][0] = *reinterpret_cast<const float4*>(ip);
            L[q][1] = *reinterpret_cast<const float4*>(ip + 4);
            L[q][2] = *reinterpret_cast<const float4*>(hp);
            L[q][3] = *reinterpret_cast<const float4*>(hp + 4);
        }
    };
    auto write_lds = [&](int buf) {
#pragma unroll
        for (int q = 0; q < 2; ++q) {
            int row = r0 + q * 16;
            short8 v;
            v[0] = f2bf(L[q][0].x + L[q][2].x);
            v[1] = f2bf(L[q][0].y + L[q][2].y);
            v[2] = f2bf(L[q][0].z + L[q][2].z);
            v[3] = f2bf(L[q][0].w + L[q][2].w);
            v[4] = f2bf(L[q][1].x + L[q][3].x);
            v[5] = f2bf(L[q][1].y + L[q][3].y);
            v[6] = f2bf(L[q][1].z + L[q][3].z);
            v[7] = f2bf(L[q][1].w + L[q][3].w);
            int byte = row * 512 + k0 * 2;
            byte ^= (row & 7) << 4;              // bank-conflict swizzle
            *reinterpret_cast<short8*>(reinterpret_cast<char*>(As[buf]) + byte) = v;
        }
    };

    float* out0 = out;                               // out gate
    float* out1 = out + (size_t)Bsz * Hdim;          // hidden_state
    float* out2 = out + (size_t)2 * Bsz * Hdim;      // cell_state

    issue(0);
    write_lds(0);
    __syncthreads();                                 // As[0] + Blds ready

#pragma unroll
    for (int t = 0; t < TPB; ++t) {
        const int cur = t & 1;

        // ---- acc init = bias (broadcast into the 4 row-slots) -------------
        f32x4 acc[4][2][2];                          // [gate][mf(rows)][jf]
#pragma unroll
        for (int g = 0; g < 4; ++g)
#pragma unroll
            for (int jf = 0; jf < 2; ++jf) {
                float b = Blds[g * Hdim + wave * 32 + jf * 16 + lm];
                f32x4 bb = (f32x4){b, b, b, b};
                acc[g][0][jf] = bb;
                acc[g][1][jf] = bb;
            }

        // ---- GEMM: K=256 in 8 steps ---------------------------------------
        const char* A = reinterpret_cast<const char*>(As[cur]);
#pragma unroll
        for (int ks = 0; ks < 8; ++ks) {
            short8 cf[2];
#pragma unroll
            for (int mf = 0; mf < 2; ++mf) {
                int row  = mf * 16 + lm;
                int byte = row * 512 + (ks * 32 + lk * 8) * 2;
                byte ^= (row & 7) << 4;
                cf[mf] = *reinterpret_cast<const short8*>(A + byte);
            }
#pragma unroll
            for (int g = 0; g < 4; ++g)
#pragma unroll
                for (int jf = 0; jf < 2; ++jf) {
                    int chunk = (g * 8 + ks) * 16 + (wave * 2 + jf);
                    short8 b = *reinterpret_cast<const short8*>(
                                   Bp + ((size_t)chunk * 64 + lane) * 8);
                    acc[g][0][jf] = __builtin_amdgcn_mfma_f32_16x16x32_bf16(cf[0], b, acc[g][0][jf], 0, 0, 0);
                    acc[g][1][jf] = __builtin_amdgcn_mfma_f32_16x16x32_bf16(cf[1], b, acc[g][1][jf], 0, 0, 0);
                }
        }

        // ---- epilogue in two row-halves; prefetch next tile between them --
#pragma unroll
        for (int mf = 0; mf < 2; ++mf) {
            // cell preload for this half (8 scalar loads, 64B-coalesced)
            float cv[2][4];
#pragma unroll
            for (int jf = 0; jf < 2; ++jf)
#pragma unroll
                for (int r = 0; r < 4; ++r) {
                    size_t off = (size_t)(rowblk + t * TROWS + mf * 16 + lk * 4 + r) * Hdim
                               + wave * 32 + jf * 16 + lm;
                    cv[jf][r] = cell[off];
                }
#pragma unroll
            for (int r = 0; r < 4; ++r) {
                float o2[2], h2[2], c2[2];
#pragma unroll
                for (int jf = 0; jf < 2; ++jf) {
                    float F = sigm(acc[0][mf][jf][r]);
                    float C = tanh_fast(acc[1][mf][jf][r]);
                    float I = sigm(sigm(acc[2][mf][jf][r]));   // double sigmoid, per ref
                    float O = sigm(acc[3][mf][jf][r]);
                    float cs = cv[jf][r] * F + C * I;
                    o2[jf] = O;
                    h2[jf] = O * tanh_fast(cs);
                    c2[jf] = cs;
                }
                // both 64B halves of each 128B line issued back-to-back
                size_t base = (size_t)(rowblk + t * TROWS + mf * 16 + lk * 4 + r) * Hdim
                            + wave * 32 + lm;
                out0[base]      = o2[0];
                out0[base + 16] = o2[1];
                out1[base]      = h2[0];
                out1[base + 16] = h2[1];
                out2[base]      = c2[0];
                out2[base + 16] = c2[1];
            }
            // issue next tile's loads after half 0 (hidden under half 1's math)
            if (mf == 0 && t + 1 < TPB) issue(t + 1);
        }

        if (t + 1 < TPB) {
            write_lds(cur ^ 1);
            __syncthreads();                         // As[cur^1] ready
        }
    }
}

extern "C" void kernel_launch(void* const* d_in, const int* in_sizes, int n_in,
                              void* d_out, int out_size, void* d_ws, size_t ws_size,
                              hipStream_t stream)
{
    const float* inp  = (const float*)d_in[0];
    const float* hid  = (const float*)d_in[1];
    const float* cell = (const float*)d_in[2];
    const float* Wf   = (const float*)d_in[3];
    const float* bf_  = (const float*)d_in[4];
    const float* Wc   = (const float*)d_in[5];
    const float* bc_  = (const float*)d_in[6];
    const float* Wi   = (const float*)d_in[7];
    const float* bi_  = (const float*)d_in[8];
    const float* Wo   = (const float*)d_in[9];
    const float* bo_  = (const float*)d_in[10];

    short* Bp = (short*)d_ws;    // 512 KB packed bf16 weights

    prep_w_kernel<<<1024, 256, 0, stream>>>(Wf, Wc, Wi, Wo, Bp);
    lstm_fused<<<GRID, 512, 0, stream>>>(inp, hid, cell, Bp,
                                         bf_, bc_, bi_, bo_, (float*)d_out);
}

// Round 5
// 138.828 us; speedup vs baseline: 2.1618x; 1.2598x over previous
//
#include <hip/hip_runtime.h>
#include <hip/hip_bf16.h>

// LSTM cell fused kernel for MI355X (gfx950).
// B=65536, H=256. Packed GEMM [B,256]x[256,1024] bf16 MFMA + fused gates.
// R5: 256-thread blocks, 32-row x 128-j tiles (grid 4096) -> 4 blocks/CU for
//     phase diversity; cell staged via LDS (latency hidden under staging);
//     XCD-paired bid swizzle so j-half twins share L2; R2 store code verbatim.

typedef __attribute__((ext_vector_type(8))) short short8;   // 8 bf16
typedef __attribute__((ext_vector_type(4))) float f32x4;

static constexpr int Bsz   = 65536;
static constexpr int Hdim  = 256;
static constexpr int TROWS = 32;
static constexpr int NBLK  = (Bsz / TROWS) * 2;   // 4096 blocks (2 j-halves)

// float -> bf16 bits, round-to-nearest-even
__device__ __forceinline__ short f2bf(float f) {
    unsigned u = __float_as_uint(f);
    return (short)((u + 0x7FFFu + ((u >> 16) & 1u)) >> 16);
}
__device__ __forceinline__ float sigm(float x) { return 1.0f / (1.0f + __expf(-x)); }
__device__ __forceinline__ float tanh_fast(float x) {
    return 2.0f / (1.0f + __expf(-2.0f * x)) - 1.0f;
}

// ---------------------------------------------------------------------------
// Pack Wf,Wc,Wi,Wo ([256,256] fp32) into bf16 B-fragment-major layout for
// mfma_f32_16x16x32_bf16 (identical to R2, verified):
//   flat o = (((g*8 + ks)*16 + jf)*64 + lane)*8 + e
//   k = ks*32 + (lane>>4)*8 + e ;  j = jf*16 + (lane&15) ;  B[k][j] = W_g[j][k]
// ---------------------------------------------------------------------------
__global__ void __launch_bounds__(256)
prep_w_kernel(const float* __restrict__ Wf, const float* __restrict__ Wc,
              const float* __restrict__ Wi, const float* __restrict__ Wo,
              short* __restrict__ Bp)
{
    int o    = blockIdx.x * 256 + threadIdx.x;   // 0 .. 262143
    int e    = o & 7;
    int lane = (o >> 3) & 63;
    int jf   = (o >> 9) & 15;
    int ks   = (o >> 13) & 7;
    int g    = (o >> 16) & 3;
    int k = ks * 32 + (lane >> 4) * 8 + e;
    int j = jf * 16 + (lane & 15);
    const float* W = (g == 0) ? Wf : (g == 1) ? Wc : (g == 2) ? Wi : Wo;
    Bp[o] = f2bf(W[j * 256 + k]);
}

// ---------------------------------------------------------------------------
// Main fused kernel. 4096 blocks x 256 threads (4 waves). Block handles
// 32 batch rows x one j-half (128 of 256 gate-cols) for all 4 gates.
// Wave w owns per-gate cols [jh*128 + w*32, +32). Single barrier per block.
// ---------------------------------------------------------------------------
__global__ void __launch_bounds__(256, 4)
lstm_fused(const float* __restrict__ inp, const float* __restrict__ hid,
           const float* __restrict__ cell, const short* __restrict__ Bp,
           const float* __restrict__ bfv, const float* __restrict__ bcv,
           const float* __restrict__ biv, const float* __restrict__ bov,
           float* __restrict__ out)
{
    __shared__ short As[TROWS * Hdim];      // 16 KB combine tile (swizzled)
    __shared__ float Cs[TROWS * 132];       // 16.5 KB cell tile (+4 pad)
    __shared__ float Blds[4 * 128];         // 2 KB biases (this j-half)

    const int tid  = threadIdx.x;
    const int lane = tid & 63;
    const int wave = tid >> 6;
    const int lm   = lane & 15;
    const int lk   = lane >> 4;

    // XCD-paired swizzle: bids 16t+k and 16t+8+k (same XCD under %8
    // round-robin) are the two j-halves of the same row-tile.
    const int bid     = blockIdx.x;
    const int rowtile = (bid >> 4) * 8 + (bid & 7);
    const int jh      = (bid >> 3) & 1;
    const int rowblk  = rowtile * TROWS;
    const int jbase   = jh * 128;

    // ---- issue combine loads (4 chunks of 8 floats per thread) ------------
    float4 Li[4][2], Lh[4][2];
#pragma unroll
    for (int c = 0; c < 4; ++c) {
        int cc  = tid + c * 256;         // chunk 0..1023
        int row = cc >> 5;               // 0..31
        int k0  = (cc & 31) * 8;         // 0..248
        const float4* ip = reinterpret_cast<const float4*>(inp + (size_t)(rowblk + row) * Hdim + k0);
        const float4* hp = reinterpret_cast<const float4*>(hid + (size_t)(rowblk + row) * Hdim + k0);
        Li[c][0] = ip[0]; Li[c][1] = ip[1];
        Lh[c][0] = hp[0]; Lh[c][1] = hp[1];
    }
    // ---- issue cell loads (this j-half: 32x128 floats) --------------------
    float4 Lc[4];
#pragma unroll
    for (int c = 0; c < 4; ++c) {
        int flat = c * 1024 + tid * 4;   // float index in 32x128 tile
        int row  = flat >> 7;
        int col  = flat & 127;
        Lc[c] = *reinterpret_cast<const float4*>(
                    cell + (size_t)(rowblk + row) * Hdim + jbase + col);
    }
    // ---- biases for this j-half ------------------------------------------
    if (tid < 128) {
        int g  = tid >> 5;
        int j4 = (tid & 31) * 4;
        const float* bp = (g == 0) ? bfv : (g == 1) ? bcv : (g == 2) ? biv : bov;
        *reinterpret_cast<float4*>(&Blds[g * 128 + j4]) =
            *reinterpret_cast<const float4*>(bp + jbase + j4);
    }

    // ---- pack combine -> As (bf16, XOR swizzle) ---------------------------
#pragma unroll
    for (int c = 0; c < 4; ++c) {
        int cc  = tid + c * 256;
        int row = cc >> 5;
        int k0  = (cc & 31) * 8;
        short8 v;
        v[0] = f2bf(Li[c][0].x + Lh[c][0].x);
        v[1] = f2bf(Li[c][0].y + Lh[c][0].y);
        v[2] = f2bf(Li[c][0].z + Lh[c][0].z);
        v[3] = f2bf(Li[c][0].w + Lh[c][0].w);
        v[4] = f2bf(Li[c][1].x + Lh[c][1].x);
        v[5] = f2bf(Li[c][1].y + Lh[c][1].y);
        v[6] = f2bf(Li[c][1].z + Lh[c][1].z);
        v[7] = f2bf(Li[c][1].w + Lh[c][1].w);
        int byte = row * 512 + k0 * 2;
        byte ^= (row & 7) << 4;
        *reinterpret_cast<short8*>(reinterpret_cast<char*>(As) + byte) = v;
    }
    // ---- cell -> Cs -------------------------------------------------------
#pragma unroll
    for (int c = 0; c < 4; ++c) {
        int flat = c * 1024 + tid * 4;
        int row  = flat >> 7;
        int col  = flat & 127;
        *reinterpret_cast<float4*>(&Cs[row * 132 + col]) = Lc[c];
    }

    __syncthreads();    // As, Cs, Blds all visible; all staging loads drained

    // ---- acc init = bias --------------------------------------------------
    f32x4 acc[4][2][2];                  // [gate][mf(rows)][jf]
#pragma unroll
    for (int g = 0; g < 4; ++g)
#pragma unroll
        for (int jf = 0; jf < 2; ++jf) {
            float b = Blds[g * 128 + wave * 32 + jf * 16 + lm];
            f32x4 bb = (f32x4){b, b, b, b};
            acc[g][0][jf] = bb;
            acc[g][1][jf] = bb;
        }

    // ---- GEMM: K=256 in 8 steps ------------------------------------------
    const char* A = reinterpret_cast<const char*>(As);
#pragma unroll
    for (int ks = 0; ks < 8; ++ks) {
        short8 cf[2];
#pragma unroll
        for (int mf = 0; mf < 2; ++mf) {
            int row  = mf * 16 + lm;
            int byte = row * 512 + (ks * 32 + lk * 8) * 2;
            byte ^= (row & 7) << 4;
            cf[mf] = *reinterpret_cast<const short8*>(A + byte);
        }
#pragma unroll
        for (int g = 0; g < 4; ++g)
#pragma unroll
            for (int jf = 0; jf < 2; ++jf) {
                int chunk = (g * 8 + ks) * 16 + jh * 8 + wave * 2 + jf;
                short8 b = *reinterpret_cast<const short8*>(
                               Bp + ((size_t)chunk * 64 + lane) * 8);
                acc[g][0][jf] = __builtin_amdgcn_mfma_f32_16x16x32_bf16(cf[0], b, acc[g][0][jf], 0, 0, 0);
                acc[g][1][jf] = __builtin_amdgcn_mfma_f32_16x16x32_bf16(cf[1], b, acc[g][1][jf], 0, 0, 0);
            }
    }

    // ---- epilogue (R2 store order, cell from LDS) -------------------------
    float* out0 = out;                               // out gate
    float* out1 = out + (size_t)Bsz * Hdim;          // hidden_state
    float* out2 = out + (size_t)2 * Bsz * Hdim;      // cell_state

    float cv[2][2][4];                               // [mf][jf][r] from LDS
#pragma unroll
    for (int mf = 0; mf < 2; ++mf)
#pragma unroll
        for (int jf = 0; jf < 2; ++jf)
#pragma unroll
            for (int r = 0; r < 4; ++r) {
                int rloc = mf * 16 + lk * 4 + r;
                int jloc = wave * 32 + jf * 16 + lm;
                cv[mf][jf][r] = Cs[rloc * 132 + jloc];
            }

#pragma unroll
    for (int jf = 0; jf < 2; ++jf) {
        int j = jbase + wave * 32 + jf * 16 + lm;
#pragma unroll
        for (int mf = 0; mf < 2; ++mf) {
#pragma unroll
            for (int r = 0; r < 4; ++r) {
                int row = rowblk + mf * 16 + lk * 4 + r;   // C/D: row=(lane>>4)*4+reg
                size_t off = (size_t)row * Hdim + j;
                float F = sigm(acc[0][mf][jf][r]);
                float C = tanh_fast(acc[1][mf][jf][r]);
                float I = sigm(sigm(acc[2][mf][jf][r]));   // double sigmoid, per ref
                float O = sigm(acc[3][mf][jf][r]);
                float cs = cv[mf][jf][r] * F + C * I;
                float hs = O * tanh_fast(cs);
                out0[off] = O;
                out1[off] = hs;
                out2[off] = cs;
            }
        }
    }
}

extern "C" void kernel_launch(void* const* d_in, const int* in_sizes, int n_in,
                              void* d_out, int out_size, void* d_ws, size_t ws_size,
                              hipStream_t stream)
{
    const float* inp  = (const float*)d_in[0];
    const float* hid  = (const float*)d_in[1];
    const float* cell = (const float*)d_in[2];
    const float* Wf   = (const float*)d_in[3];
    const float* bf_  = (const float*)d_in[4];
    const float* Wc   = (const float*)d_in[5];
    const float* bc_  = (const float*)d_in[6];
    const float* Wi   = (const float*)d_in[7];
    const float* bi_  = (const float*)d_in[8];
    const float* Wo   = (const float*)d_in[9];
    const float* bo_  = (const float*)d_in[10];

    short* Bp = (short*)d_ws;    // 512 KB packed bf16 weights

    prep_w_kernel<<<1024, 256, 0, stream>>>(Wf, Wc, Wi, Wo, Bp);
    lstm_fused<<<NBLK, 256, 0, stream>>>(inp, hid, cell, Bp,
                                         bf_, bc_, bi_, bo_, (float*)d_out);
}